// Round 2
// baseline (127.111 us; speedup 1.0000x reference)
//
#include <hip/hip_runtime.h>
#include <math.h>

#define BATCH 128
#define NNODE 512
#define RU 64
#define MEM_DIM 16
#define BOT_DIM 4
#define IN_SZ 66
#define OUT_SZ 256
#define HID (NNODE*RU)          // 32768
#define W3_ROW 16896            // IN_SZ*OUT_SZ

typedef _Float16 half8 __attribute__((ext_vector_type(8)));
typedef __attribute__((ext_vector_type(4))) float float4v;

__device__ __forceinline__ float fsig(float x) {
    return __builtin_amdgcn_rcpf(1.0f + __expf(-x));
}
__device__ __forceinline__ float ftanh(float x) {
    return 1.0f - 2.0f * __builtin_amdgcn_rcpf(1.0f + __expf(2.0f * x));
}

// ---------------- single fused kernel: block = (node, output-half) ------------
// No prep kernel, no workspace. Each block:
//   1. issues A/cx HBM loads early
//   2. computes the per-node hypernet m2 (lane-parallel, overlaps load latency)
//   3. combine: gathers w3/b3 fp32 directly from L2/L3 (zero slots skipped),
//      fp32 fma with m2 coeffs, converts fp16, stages MFMA B-frags in LDS
//   4. one barrier -> MFMA -> epilogue (b_out loaded post-MFMA to save regs)
// Frag layout (unchanged): fl = ctl*3+ks, ct = h*8+ctl;
//   col o = (ct&3)*64+(ct>>2)*16+q ; slot s = ks*32+quad*8+j ;
//   s<64 -> W row i=s+2 ; s=64,65 -> i=0,1 (input rows) ; else 0.
__global__ __launch_bounds__(256, 4) void fused_kernel(
    const float* __restrict__ inputs, const float* __restrict__ hx,
    const float* __restrict__ cx,     const float* __restrict__ b_out,
    const float* __restrict__ memory, const float* __restrict__ w1,
    const float* __restrict__ b1,     const float* __restrict__ w2,
    const float* __restrict__ b2,     const float* __restrict__ w3,
    const float* __restrict__ b3,     float* __restrict__ out)
{
    __shared__ _Float16 Wl[24 * 512];   // 24576 B, single buffer
    const int tid  = threadIdx.x;
    const int n    = blockIdx.x & 511;
    const int h    = blockIdx.x >> 9;
    const int w    = tid >> 6;
    const int lane = tid & 63;
    const int q    = lane & 15;
    const int quad = lane >> 4;

    // ---- A loads (HBM; issue first) ----
    float4v xa[2][4];
    float xin[2][2];
    #pragma unroll
    for (int rt = 0; rt < 2; ++rt) {
        const int row = w * 32 + rt * 16 + q;
        const float* hrow = hx + (size_t)row * HID + n * RU + quad * 8;
        xa[rt][0] = *(const float4v*)(hrow);
        xa[rt][1] = *(const float4v*)(hrow + 4);
        xa[rt][2] = *(const float4v*)(hrow + 32);
        xa[rt][3] = *(const float4v*)(hrow + 36);
        if (quad == 0) {
            const float* ip = inputs + (size_t)row * (NNODE * 2) + n * 2;
            xin[rt][0] = ip[0];
            xin[rt][1] = ip[1];
        } else {
            xin[rt][0] = 0.f;
            xin[rt][1] = 0.f;
        }
    }

    // cx for this half (issue early; consumed only in epilogue)
    float cxr[2][4][2];
    #pragma unroll
    for (int rt = 0; rt < 2; ++rt)
        #pragma unroll
        for (int v = 0; v < 4; ++v) {
            const int b = w * 32 + rt * 16 + quad * 4 + v;
            #pragma unroll
            for (int rh = 0; rh < 2; ++rh)
                cxr[rt][v][rh] = cx[(size_t)b * HID + n * RU + h * 32 + rh * 16 + q];
        }

    // ---- pack A to fp16 now (frees xa before combine's register peak) ----
    half8 a[3][2];
    #pragma unroll
    for (int rt = 0; rt < 2; ++rt) {
        #pragma unroll
        for (int ksh = 0; ksh < 2; ++ksh) {
            const float4v lo = xa[rt][ksh * 2];
            const float4v hi = xa[rt][ksh * 2 + 1];
            half8 t;
            t[0] = (_Float16)lo[0]; t[1] = (_Float16)lo[1];
            t[2] = (_Float16)lo[2]; t[3] = (_Float16)lo[3];
            t[4] = (_Float16)hi[0]; t[5] = (_Float16)hi[1];
            t[6] = (_Float16)hi[2]; t[7] = (_Float16)hi[3];
            a[ksh][rt] = t;
        }
        half8 t2 = (half8){0, 0, 0, 0, 0, 0, 0, 0};
        t2[0] = (_Float16)xin[rt][0];
        t2[1] = (_Float16)xin[rt][1];
        a[2][rt] = t2;
    }

    // ---- hypernet: m2 = tanh(tanh(memory@w1+b1)@w2+b2), lane-parallel ----
    // lane l computes mem1[l&15]; layer2 via width-16 shuffle broadcast.
    const int t16 = q;
    float s1 = b1[t16];
    #pragma unroll
    for (int j = 0; j < MEM_DIM; ++j)
        s1 = fmaf(memory[n * MEM_DIM + j], w1[j * MEM_DIM + t16], s1);
    const float mem1 = ftanh(s1);
    float c[4];
    #pragma unroll
    for (int t = 0; t < 4; ++t) c[t] = b2[t];
    #pragma unroll
    for (int j = 0; j < MEM_DIM; ++j) {
        const float mj = __shfl(mem1, j, 16);
        #pragma unroll
        for (int t = 0; t < 4; ++t) c[t] = fmaf(mj, w2[j * BOT_DIM + t], c[t]);
    }
    #pragma unroll
    for (int t = 0; t < 4; ++t) c[t] = ftanh(c[t]);

    // ---- combine: direct fp32 gather from w3/b3, fp16 result to LDS ----
    // wave w handles frag fl = it*4 + w each iteration (l = lane).
    #pragma unroll
    for (int it = 0; it < 6; ++it) {
        const int fl  = it * 4 + w;
        const int ctl = fl / 3;
        const int ks  = fl - ctl * 3;
        const int ct  = h * 8 + ctl;
        const int o   = (ct & 3) * 64 + (ct >> 2) * 16 + q;
        half8 r;
        if (ks < 2) {
            const int ibase = ks * 32 + quad * 8 + 2;   // W row i = s+2
            #pragma unroll
            for (int j = 0; j < 8; ++j) {
                const int off = (ibase + j) * OUT_SZ + o;
                float x = b3[off];
                x = fmaf(c[0], w3[off], x);
                x = fmaf(c[1], w3[W3_ROW + off], x);
                x = fmaf(c[2], w3[2 * W3_ROW + off], x);
                x = fmaf(c[3], w3[3 * W3_ROW + off], x);
                r[j] = (_Float16)x;
            }
        } else {
            #pragma unroll
            for (int j = 0; j < 8; ++j) r[j] = (_Float16)0.f;
            if (quad == 0) {
                #pragma unroll
                for (int j = 0; j < 2; ++j) {            // input rows i = 0,1
                    const int off = j * OUT_SZ + o;
                    float x = b3[off];
                    x = fmaf(c[0], w3[off], x);
                    x = fmaf(c[1], w3[W3_ROW + off], x);
                    x = fmaf(c[2], w3[2 * W3_ROW + off], x);
                    x = fmaf(c[3], w3[3 * W3_ROW + off], x);
                    r[j] = (_Float16)x;
                }
            }
        }
        *(half8*)(&Wl[fl * 512 + lane * 8]) = r;
    }

    float4v acc[2][8];
    #pragma unroll
    for (int rt = 0; rt < 2; ++rt)
        #pragma unroll
        for (int ctl = 0; ctl < 8; ++ctl)
            acc[rt][ctl] = (float4v){0.f, 0.f, 0.f, 0.f};

    __syncthreads();        // the ONLY barrier

    // ---- MFMA ----
    __builtin_amdgcn_s_setprio(1);
    #pragma unroll
    for (int ks = 0; ks < 3; ++ks)
        #pragma unroll
        for (int ctl = 0; ctl < 8; ++ctl) {
            const half8 bf = *(const half8*)(&Wl[(ctl * 3 + ks) * 512 + lane * 8]);
            acc[0][ctl] = __builtin_amdgcn_mfma_f32_16x16x32_f16(a[ks][0], bf, acc[0][ctl], 0, 0, 0);
            acc[1][ctl] = __builtin_amdgcn_mfma_f32_16x16x32_f16(a[ks][1], bf, acc[1][ctl], 0, 0, 0);
        }
    __builtin_amdgcn_s_setprio(0);

    // b_out for this half (deferred past MFMA to cut register peak; L2-hot)
    float bo[2][4];
    #pragma unroll
    for (int rh = 0; rh < 2; ++rh)
        #pragma unroll
        for (int g = 0; g < 4; ++g)
            bo[rh][g] = b_out[g * 64 + h * 32 + rh * 16 + q];

    // ---- epilogue + stores ----
    #pragma unroll
    for (int rt = 0; rt < 2; ++rt)
        #pragma unroll
        for (int v = 0; v < 4; ++v) {
            const int b = w * 32 + rt * 16 + quad * 4 + v;
            const size_t base = (size_t)b * HID + n * RU + h * 32;
            #pragma unroll
            for (int rh = 0; rh < 2; ++rh) {
                // reference: val = sigmoid(matmul) + b_out, THEN gate activations
                float vi = fsig(acc[rt][rh * 4 + 0][v]) + bo[rh][0];
                float vf = fsig(acc[rt][rh * 4 + 1][v]) + bo[rh][1];
                float vg = fsig(acc[rt][rh * 4 + 2][v]) + bo[rh][2];
                float vo = fsig(acc[rt][rh * 4 + 3][v]) + bo[rh][3];
                float it = fsig(vi), ft = fsig(vf);
                float gt = ftanh(vg), ot = fsig(vo);
                float cc = cxr[rt][v][rh] * ft + it * gt;
                const size_t idx = base + rh * 16 + q;
                out[idx] = ot * ftanh(cc);               // hy
                out[(size_t)BATCH * HID + idx] = cc;     // cy
            }
        }
}

extern "C" void kernel_launch(void* const* d_in, const int* in_sizes, int n_in,
                              void* d_out, int out_size, void* d_ws, size_t ws_size,
                              hipStream_t stream) {
    const float* inputs = (const float*)d_in[0];
    const float* hx     = (const float*)d_in[1];
    const float* cx     = (const float*)d_in[2];
    const float* memory = (const float*)d_in[3];
    const float* w1     = (const float*)d_in[4];
    const float* b1     = (const float*)d_in[5];
    const float* w2     = (const float*)d_in[6];
    const float* b2     = (const float*)d_in[7];
    const float* w3     = (const float*)d_in[8];
    const float* b3     = (const float*)d_in[9];
    const float* b_out  = (const float*)d_in[10];
    float* out = (float*)d_out;

    (void)d_ws; (void)ws_size;   // workspace intentionally unused

    fused_kernel<<<2 * NNODE, 256, 0, stream>>>(
        inputs, hx, cx, b_out, memory, w1, b1, w2, b2, w3, b3, out);
}

// Round 3
// 124.293 us; speedup vs baseline: 1.0227x; 1.0227x over previous
//
#include <hip/hip_runtime.h>
#include <math.h>

#define BATCH 128
#define NNODE 512
#define RU 64
#define MEM_DIM 16
#define BOT_DIM 4
#define IN_SZ 66
#define OUT_SZ 256
#define HID (NNODE*RU)          // 32768
#define W3_ROW 16896            // IN_SZ*OUT_SZ
// fp16 frag table: frag f = k*48 + h*24 + fl, fl = ctl*3+ks (ct = h*8+ctl);
// element = lane*8+j. col o = (ct&3)*64+(ct>>2)*16+(lane&15);
// slot s = ks*32+(lane>>4)*8+j ; s<64 -> W row i=s+2 ; s=64,65 -> i=0,1 ; else 0.
#define TAB_HALVES (240*512)    // 122880 halves = 245760 B
#define KSTEP (48*512)          // halves between k-matrices

typedef _Float16 half8 __attribute__((ext_vector_type(8)));
typedef __attribute__((ext_vector_type(4))) float float4v;

__device__ __forceinline__ float fsig(float x) {
    return __builtin_amdgcn_rcpf(1.0f + __expf(-x));
}
__device__ __forceinline__ float ftanh(float x) {
    return 1.0f - 2.0f * __builtin_amdgcn_rcpf(1.0f + __expf(2.0f * x));
}

// ---------------- Kernel 1: prep — fp16 frag table + hypernet m2 --------------
// 248 blocks x 64 threads (1 wave each) -> ~248 CUs active.
// Blocks [0,240): one frag per block. Blocks [240,248): hypernet, 64 nodes each.
__global__ __launch_bounds__(64) void prep_kernel(
    const float* __restrict__ memory, const float* __restrict__ w1,
    const float* __restrict__ b1,     const float* __restrict__ w2,
    const float* __restrict__ b2,     const float* __restrict__ w3,
    const float* __restrict__ b3,     _Float16* __restrict__ tab,
    float* __restrict__ m2_ws)
{
    const int tid = threadIdx.x;
    const int bid = blockIdx.x;
    if (bid < 240) {
        const int f = bid;                  // frag [0,240)
        const int l = tid;                  // [0,64)
        const int k   = f / 48;             // [0,5): w3 rows 0..3, then b3
        const int rem = f - k * 48;         // = ct*3 + ks, ct = h*8+ctl
        const int ct  = rem / 3;
        const int ks  = rem - ct * 3;
        const int q = l & 15, quad = l >> 4;
        const int o = (ct & 3) * 64 + (ct >> 2) * 16 + q;
        const float* src = (k < 4) ? (w3 + k * W3_ROW) : b3;
        half8 v;
        #pragma unroll
        for (int j = 0; j < 8; ++j) {
            const int s = ks * 32 + quad * 8 + j;
            float x = 0.f;
            if (s < IN_SZ) {
                const int i = (s < 64) ? s + 2 : s - 64;
                x = src[i * OUT_SZ + o];
            }
            v[j] = (_Float16)x;
        }
        *(half8*)(tab + f * 512 + l * 8) = v;
    } else {
        const int n = (bid - 240) * 64 + tid;   // [0,512)
        float memv[MEM_DIM];
        #pragma unroll
        for (int j = 0; j < MEM_DIM; ++j) memv[j] = memory[n * MEM_DIM + j];
        float mem1[MEM_DIM];
        #pragma unroll
        for (int t = 0; t < MEM_DIM; ++t) {
            float s = b1[t];
            #pragma unroll
            for (int j = 0; j < MEM_DIM; ++j) s += memv[j] * w1[j * MEM_DIM + t];
            mem1[t] = ftanh(s);
        }
        #pragma unroll
        for (int t = 0; t < BOT_DIM; ++t) {
            float s = b2[t];
            #pragma unroll
            for (int j = 0; j < MEM_DIM; ++j) s += mem1[j] * w2[j * BOT_DIM + t];
            m2_ws[n * 4 + t] = ftanh(s);
        }
    }
}

// ---------------- Kernel 2: fused — block = (node, output-half) ---------------
// Pair-adjacent swizzle: n = (bid>>4)*8 + (bid&7), h = (bid>>3)&1.
// The two blocks of node n are 8 dispatch slots apart (concurrent) AND on the
// same XCD (bid ≡ bid+8 mod 8) -> the duplicated full-width hx read is an L2
// hit instead of a second HBM read (saves ~16 MB HBM).
__global__ __launch_bounds__(256) void fused_kernel(
    const float* __restrict__ inputs, const float* __restrict__ hx,
    const float* __restrict__ cx,     const float* __restrict__ b_out,
    const _Float16* __restrict__ tab, const float* __restrict__ m2_ws,
    float* __restrict__ out)
{
    __shared__ _Float16 Wl[24 * 512];   // 24576 B, single buffer
    const int tid  = threadIdx.x;
    const int n    = (blockIdx.x >> 4) * 8 + (blockIdx.x & 7);
    const int h    = (blockIdx.x >> 3) & 1;
    const int w    = tid >> 6;
    const int lane = tid & 63;
    const int q    = lane & 15;
    const int quad = lane >> 4;

    // coef splat (fp16 for pk_fma combine)
    const float4v m2v = *(const float4v*)(m2_ws + n * 4);
    half8 vc[4];
    #pragma unroll
    for (int k = 0; k < 4; ++k) {
        const _Float16 c = (_Float16)m2v[k];
        vc[k] = (half8){c, c, c, c, c, c, c, c};
    }

    // ---- A loads (HBM once per pair; partner block hits L2) ----
    float4v xa[2][4];
    float xin[2][2];
    #pragma unroll
    for (int rt = 0; rt < 2; ++rt) {
        const int row = w * 32 + rt * 16 + q;
        const float* hrow = hx + (size_t)row * HID + n * RU + quad * 8;
        xa[rt][0] = *(const float4v*)(hrow);
        xa[rt][1] = *(const float4v*)(hrow + 4);
        xa[rt][2] = *(const float4v*)(hrow + 32);
        xa[rt][3] = *(const float4v*)(hrow + 36);
        if (quad == 0) {
            const float* ip = inputs + (size_t)row * (NNODE * 2) + n * 2;
            xin[rt][0] = ip[0];
            xin[rt][1] = ip[1];
        } else {
            xin[rt][0] = 0.f;
            xin[rt][1] = 0.f;
        }
    }

    // cx for this half (issue early; consumed only in epilogue)
    float cxr[2][4][2];
    #pragma unroll
    for (int rt = 0; rt < 2; ++rt)
        #pragma unroll
        for (int v = 0; v < 4; ++v) {
            const int b = w * 32 + rt * 16 + quad * 4 + v;
            #pragma unroll
            for (int rh = 0; rh < 2; ++rh)
                cxr[rt][v][rh] = cx[(size_t)b * HID + n * RU + h * 32 + rh * 16 + q];
        }

    // ---- combine this half -> Wl (fp16 pk_fma); L2-resident tab ----
    #pragma unroll
    for (int it = 0; it < 6; ++it) {
        const int c  = it * 256 + tid;
        const int fl = c >> 6;
        const int l  = c & 63;
        const _Float16* p = tab + (h * 24 + fl) * 512 + l * 8;
        half8 r = *(const half8*)(p + 4 * KSTEP);     // b3 frag
        r += vc[0] * *(const half8*)(p);
        r += vc[1] * *(const half8*)(p + KSTEP);
        r += vc[2] * *(const half8*)(p + 2 * KSTEP);
        r += vc[3] * *(const half8*)(p + 3 * KSTEP);
        *(half8*)(&Wl[fl * 512 + l * 8]) = r;
    }

    // ---- pack A to fp16 ----
    half8 a[3][2];
    #pragma unroll
    for (int rt = 0; rt < 2; ++rt) {
        #pragma unroll
        for (int ksh = 0; ksh < 2; ++ksh) {
            const float4v lo = xa[rt][ksh * 2];
            const float4v hi = xa[rt][ksh * 2 + 1];
            half8 t;
            t[0] = (_Float16)lo[0]; t[1] = (_Float16)lo[1];
            t[2] = (_Float16)lo[2]; t[3] = (_Float16)lo[3];
            t[4] = (_Float16)hi[0]; t[5] = (_Float16)hi[1];
            t[6] = (_Float16)hi[2]; t[7] = (_Float16)hi[3];
            a[ksh][rt] = t;
        }
        half8 t2 = (half8){0, 0, 0, 0, 0, 0, 0, 0};
        t2[0] = (_Float16)xin[rt][0];
        t2[1] = (_Float16)xin[rt][1];
        a[2][rt] = t2;
    }

    float4v acc[2][8];
    #pragma unroll
    for (int rt = 0; rt < 2; ++rt)
        #pragma unroll
        for (int ctl = 0; ctl < 8; ++ctl)
            acc[rt][ctl] = (float4v){0.f, 0.f, 0.f, 0.f};

    __syncthreads();        // the ONLY barrier

    // ---- MFMA ----
    __builtin_amdgcn_s_setprio(1);
    #pragma unroll
    for (int ks = 0; ks < 3; ++ks)
        #pragma unroll
        for (int ctl = 0; ctl < 8; ++ctl) {
            const half8 bf = *(const half8*)(&Wl[(ctl * 3 + ks) * 512 + lane * 8]);
            acc[0][ctl] = __builtin_amdgcn_mfma_f32_16x16x32_f16(a[ks][0], bf, acc[0][ctl], 0, 0, 0);
            acc[1][ctl] = __builtin_amdgcn_mfma_f32_16x16x32_f16(a[ks][1], bf, acc[1][ctl], 0, 0, 0);
        }
    __builtin_amdgcn_s_setprio(0);

    // b_out for this half (deferred past MFMA to cut register peak; L2-hot)
    float bo[2][4];
    #pragma unroll
    for (int rh = 0; rh < 2; ++rh)
        #pragma unroll
        for (int g = 0; g < 4; ++g)
            bo[rh][g] = b_out[g * 64 + h * 32 + rh * 16 + q];

    // ---- epilogue + stores ----
    #pragma unroll
    for (int rt = 0; rt < 2; ++rt)
        #pragma unroll
        for (int v = 0; v < 4; ++v) {
            const int b = w * 32 + rt * 16 + quad * 4 + v;
            const size_t base = (size_t)b * HID + n * RU + h * 32;
            #pragma unroll
            for (int rh = 0; rh < 2; ++rh) {
                // reference: val = sigmoid(matmul) + b_out, THEN gate activations
                float vi = fsig(acc[rt][rh * 4 + 0][v]) + bo[rh][0];
                float vf = fsig(acc[rt][rh * 4 + 1][v]) + bo[rh][1];
                float vg = fsig(acc[rt][rh * 4 + 2][v]) + bo[rh][2];
                float vo = fsig(acc[rt][rh * 4 + 3][v]) + bo[rh][3];
                float it = fsig(vi), ft = fsig(vf);
                float gt = ftanh(vg), ot = fsig(vo);
                float cc = cxr[rt][v][rh] * ft + it * gt;
                const size_t idx = base + rh * 16 + q;
                out[idx] = ot * ftanh(cc);               // hy
                out[(size_t)BATCH * HID + idx] = cc;     // cy
            }
        }
}

extern "C" void kernel_launch(void* const* d_in, const int* in_sizes, int n_in,
                              void* d_out, int out_size, void* d_ws, size_t ws_size,
                              hipStream_t stream) {
    const float* inputs = (const float*)d_in[0];
    const float* hx     = (const float*)d_in[1];
    const float* cx     = (const float*)d_in[2];
    const float* memory = (const float*)d_in[3];
    const float* w1     = (const float*)d_in[4];
    const float* b1     = (const float*)d_in[5];
    const float* w2     = (const float*)d_in[6];
    const float* b2     = (const float*)d_in[7];
    const float* w3     = (const float*)d_in[8];
    const float* b3     = (const float*)d_in[9];
    const float* b_out  = (const float*)d_in[10];
    float* out = (float*)d_out;

    _Float16* tab = (_Float16*)d_ws;                      // 245760 B
    float* m2_ws  = (float*)((char*)d_ws + TAB_HALVES * 2);

    prep_kernel<<<248, 64, 0, stream>>>(memory, w1, b1, w2, b2, w3, b3, tab, m2_ws);
    fused_kernel<<<2 * NNODE, 256, 0, stream>>>(inputs, hx, cx, b_out, tab, m2_ws, out);
}

// Round 4
// 122.848 us; speedup vs baseline: 1.0347x; 1.0118x over previous
//
#include <hip/hip_runtime.h>
#include <math.h>

#define BATCH 128
#define NNODE 512
#define RU 64
#define MEM_DIM 16
#define BOT_DIM 4
#define IN_SZ 66
#define OUT_SZ 256
#define HID (NNODE*RU)          // 32768
#define W3_ROW 16896            // IN_SZ*OUT_SZ
// fp16 frag table: frag f = k*48 + h*24 + fl, fl = ctl*3+ks (ct = h*8+ctl);
// element = lane*8+j. col o = (ct&3)*64+(ct>>2)*16+(lane&15);
// slot s = ks*32+(lane>>4)*8+j ; s<64 -> W row i=s+2 ; s=64,65 -> i=0,1 ; else 0.
#define TAB_HALVES (240*512)    // 122880 halves = 245760 B
#define KSTEP (48*512)          // halves between k-matrices

typedef _Float16 half8 __attribute__((ext_vector_type(8)));
typedef __attribute__((ext_vector_type(4))) float float4v;

__device__ __forceinline__ float fsig(float x) {
    return __builtin_amdgcn_rcpf(1.0f + __expf(-x));
}
__device__ __forceinline__ float ftanh(float x) {
    return 1.0f - 2.0f * __builtin_amdgcn_rcpf(1.0f + __expf(2.0f * x));
}

// ---------------- Kernel 1: prep — fp16 frag table + hypernet m2 --------------
// 248 blocks x 64 threads (1 wave each) -> ~248 CUs active.
// Blocks [0,240): one frag per block. Blocks [240,248): hypernet, 64 nodes each.
__global__ __launch_bounds__(64) void prep_kernel(
    const float* __restrict__ memory, const float* __restrict__ w1,
    const float* __restrict__ b1,     const float* __restrict__ w2,
    const float* __restrict__ b2,     const float* __restrict__ w3,
    const float* __restrict__ b3,     _Float16* __restrict__ tab,
    float* __restrict__ m2_ws)
{
    const int tid = threadIdx.x;
    const int bid = blockIdx.x;
    if (bid < 240) {
        const int f = bid;                  // frag [0,240)
        const int l = tid;                  // [0,64)
        const int k   = f / 48;             // [0,5): w3 rows 0..3, then b3
        const int rem = f - k * 48;         // = ct*3 + ks, ct = h*8+ctl
        const int ct  = rem / 3;
        const int ks  = rem - ct * 3;
        const int q = l & 15, quad = l >> 4;
        const int o = (ct & 3) * 64 + (ct >> 2) * 16 + q;
        const float* src = (k < 4) ? (w3 + k * W3_ROW) : b3;
        half8 v;
        #pragma unroll
        for (int j = 0; j < 8; ++j) {
            const int s = ks * 32 + quad * 8 + j;
            float x = 0.f;
            if (s < IN_SZ) {
                const int i = (s < 64) ? s + 2 : s - 64;
                x = src[i * OUT_SZ + o];
            }
            v[j] = (_Float16)x;
        }
        *(half8*)(tab + f * 512 + l * 8) = v;
    } else {
        const int n = (bid - 240) * 64 + tid;   // [0,512)
        float memv[MEM_DIM];
        #pragma unroll
        for (int j = 0; j < MEM_DIM; ++j) memv[j] = memory[n * MEM_DIM + j];
        float mem1[MEM_DIM];
        #pragma unroll
        for (int t = 0; t < MEM_DIM; ++t) {
            float s = b1[t];
            #pragma unroll
            for (int j = 0; j < MEM_DIM; ++j) s += memv[j] * w1[j * MEM_DIM + t];
            mem1[t] = ftanh(s);
        }
        #pragma unroll
        for (int t = 0; t < BOT_DIM; ++t) {
            float s = b2[t];
            #pragma unroll
            for (int j = 0; j < MEM_DIM; ++j) s += mem1[j] * w2[j * BOT_DIM + t];
            m2_ws[n * 4 + t] = ftanh(s);
        }
    }
}

// ---------------- Kernel 2: fused — block = (node-PAIR, output-half) ----------
// 512 blocks x 512 threads (8 waves x 16 batch rows). Two adjacent nodes share
// one tab-slice read (combine L2 traffic halved: 123->61 MB) and make hx reads
// 512B-contiguous per row. LDS 48KB -> exactly 2 blocks/CU, single-pass grid.
// (p,h=0) and (p,h=1) are 256 apart (256%8==0) -> same XCD, hx dedup in L2.
__global__ __launch_bounds__(512, 4) void fused_kernel(
    const float* __restrict__ inputs, const float* __restrict__ hx,
    const float* __restrict__ cx,     const float* __restrict__ b_out,
    const _Float16* __restrict__ tab, const float* __restrict__ m2_ws,
    float* __restrict__ out)
{
    __shared__ _Float16 Wl[2][24 * 512];   // 48 KB
    const int tid  = threadIdx.x;
    const int p    = blockIdx.x & 255;
    const int h    = blockIdx.x >> 8;
    const int n0   = p * 2;
    const int w    = tid >> 6;
    const int lane = tid & 63;
    const int q    = lane & 15;
    const int quad = lane >> 4;

    // m2 coeffs for both nodes (fp16 splats for pk_fma combine)
    const float4v m2a = *(const float4v*)(m2_ws + n0 * 4);
    const float4v m2b = *(const float4v*)(m2_ws + n0 * 4 + 4);
    half8 vc[2][4];
    #pragma unroll
    for (int k = 0; k < 4; ++k) {
        const _Float16 c0 = (_Float16)m2a[k];
        const _Float16 c1 = (_Float16)m2b[k];
        vc[0][k] = (half8){c0, c0, c0, c0, c0, c0, c0, c0};
        vc[1][k] = (half8){c1, c1, c1, c1, c1, c1, c1, c1};
    }

    // ---- A loads: row r, both nodes = 512B contiguous; pack per node ----
    const int r = w * 16 + q;
    const float* hrow = hx + (size_t)r * HID + n0 * RU + quad * 8;
    float4v xinv = (float4v){0.f, 0.f, 0.f, 0.f};
    if (quad == 0)
        xinv = *(const float4v*)(inputs + (size_t)r * (NNODE * 2) + n0 * 2);
    half8 a[2][3];
    #pragma unroll
    for (int nd = 0; nd < 2; ++nd) {
        const float4v x0 = *(const float4v*)(hrow + nd * RU);
        const float4v x1 = *(const float4v*)(hrow + nd * RU + 4);
        const float4v x2 = *(const float4v*)(hrow + nd * RU + 32);
        const float4v x3 = *(const float4v*)(hrow + nd * RU + 36);
        half8 t;
        t[0] = (_Float16)x0[0]; t[1] = (_Float16)x0[1];
        t[2] = (_Float16)x0[2]; t[3] = (_Float16)x0[3];
        t[4] = (_Float16)x1[0]; t[5] = (_Float16)x1[1];
        t[6] = (_Float16)x1[2]; t[7] = (_Float16)x1[3];
        a[nd][0] = t;
        half8 u;
        u[0] = (_Float16)x2[0]; u[1] = (_Float16)x2[1];
        u[2] = (_Float16)x2[2]; u[3] = (_Float16)x2[3];
        u[4] = (_Float16)x3[0]; u[5] = (_Float16)x3[1];
        u[6] = (_Float16)x3[2]; u[7] = (_Float16)x3[3];
        a[nd][1] = u;
        half8 t2 = (half8){0, 0, 0, 0, 0, 0, 0, 0};
        t2[0] = (_Float16)xinv[nd * 2];
        t2[1] = (_Float16)xinv[nd * 2 + 1];
        a[nd][2] = t2;
    }

    // cx for this half, both nodes (consumed only in epilogue)
    float cxr[2][4][2];
    #pragma unroll
    for (int nd = 0; nd < 2; ++nd)
        #pragma unroll
        for (int v = 0; v < 4; ++v) {
            const int b = w * 16 + quad * 4 + v;
            #pragma unroll
            for (int rh = 0; rh < 2; ++rh)
                cxr[nd][v][rh] = cx[(size_t)b * HID + (n0 + nd) * RU + h * 32 + rh * 16 + q];
        }

    // b_out (node-independent)
    float bo[2][4];
    #pragma unroll
    for (int rh = 0; rh < 2; ++rh)
        #pragma unroll
        for (int g = 0; g < 4; ++g)
            bo[rh][g] = b_out[g * 64 + h * 32 + rh * 16 + q];

    // ---- combine: ONE tab-slice read serves both nodes (fma order = R1) ----
    #pragma unroll
    for (int t = 0; t < 3; ++t) {
        const int fl = t * 8 + w;
        const _Float16* pp = tab + (h * 24 + fl) * 512 + lane * 8;
        const half8 t0 = *(const half8*)(pp);
        const half8 t1 = *(const half8*)(pp + KSTEP);
        const half8 t2 = *(const half8*)(pp + 2 * KSTEP);
        const half8 t3 = *(const half8*)(pp + 3 * KSTEP);
        const half8 tb = *(const half8*)(pp + 4 * KSTEP);
        half8 r0 = tb;
        r0 += vc[0][0] * t0; r0 += vc[0][1] * t1;
        r0 += vc[0][2] * t2; r0 += vc[0][3] * t3;
        half8 r1 = tb;
        r1 += vc[1][0] * t0; r1 += vc[1][1] * t1;
        r1 += vc[1][2] * t2; r1 += vc[1][3] * t3;
        *(half8*)(&Wl[0][fl * 512 + lane * 8]) = r0;
        *(half8*)(&Wl[1][fl * 512 + lane * 8]) = r1;
    }

    float4v acc[2][8];
    #pragma unroll
    for (int nd = 0; nd < 2; ++nd)
        #pragma unroll
        for (int ctl = 0; ctl < 8; ++ctl)
            acc[nd][ctl] = (float4v){0.f, 0.f, 0.f, 0.f};

    __syncthreads();        // the ONLY barrier

    // ---- MFMA (block-diagonal: each node's A meets only its own W) ----
    __builtin_amdgcn_s_setprio(1);
    #pragma unroll
    for (int ks = 0; ks < 3; ++ks)
        #pragma unroll
        for (int ctl = 0; ctl < 8; ++ctl) {
            const half8 b0 = *(const half8*)(&Wl[0][(ctl * 3 + ks) * 512 + lane * 8]);
            acc[0][ctl] = __builtin_amdgcn_mfma_f32_16x16x32_f16(a[0][ks], b0, acc[0][ctl], 0, 0, 0);
            const half8 b1 = *(const half8*)(&Wl[1][(ctl * 3 + ks) * 512 + lane * 8]);
            acc[1][ctl] = __builtin_amdgcn_mfma_f32_16x16x32_f16(a[1][ks], b1, acc[1][ctl], 0, 0, 0);
        }
    __builtin_amdgcn_s_setprio(0);

    // ---- epilogue + stores ----
    #pragma unroll
    for (int nd = 0; nd < 2; ++nd)
        #pragma unroll
        for (int v = 0; v < 4; ++v) {
            const int b = w * 16 + quad * 4 + v;
            const size_t base = (size_t)b * HID + (n0 + nd) * RU + h * 32;
            #pragma unroll
            for (int rh = 0; rh < 2; ++rh) {
                // reference: val = sigmoid(matmul) + b_out, THEN gate activations
                float vi = fsig(acc[nd][rh * 4 + 0][v]) + bo[rh][0];
                float vf = fsig(acc[nd][rh * 4 + 1][v]) + bo[rh][1];
                float vg = fsig(acc[nd][rh * 4 + 2][v]) + bo[rh][2];
                float vo = fsig(acc[nd][rh * 4 + 3][v]) + bo[rh][3];
                float it = fsig(vi), ft = fsig(vf);
                float gt = ftanh(vg), ot = fsig(vo);
                float cc = cxr[nd][v][rh] * ft + it * gt;
                const size_t idx = base + rh * 16 + q;
                out[idx] = ot * ftanh(cc);               // hy
                out[(size_t)BATCH * HID + idx] = cc;     // cy
            }
        }
}

extern "C" void kernel_launch(void* const* d_in, const int* in_sizes, int n_in,
                              void* d_out, int out_size, void* d_ws, size_t ws_size,
                              hipStream_t stream) {
    const float* inputs = (const float*)d_in[0];
    const float* hx     = (const float*)d_in[1];
    const float* cx     = (const float*)d_in[2];
    const float* memory = (const float*)d_in[3];
    const float* w1     = (const float*)d_in[4];
    const float* b1     = (const float*)d_in[5];
    const float* w2     = (const float*)d_in[6];
    const float* b2     = (const float*)d_in[7];
    const float* w3     = (const float*)d_in[8];
    const float* b3     = (const float*)d_in[9];
    const float* b_out  = (const float*)d_in[10];
    float* out = (float*)d_out;

    _Float16* tab = (_Float16*)d_ws;                      // 245760 B
    float* m2_ws  = (float*)((char*)d_ws + TAB_HALVES * 2);

    prep_kernel<<<248, 64, 0, stream>>>(memory, w1, b1, w2, b2, w3, b3, tab, m2_ws);
    fused_kernel<<<512, 512, 0, stream>>>(inputs, hx, cx, b_out, tab, m2_ws, out);
}

// Round 6
// 119.438 us; speedup vs baseline: 1.0642x; 1.0286x over previous
//
#include <hip/hip_runtime.h>
#include <math.h>

#define BATCH 128
#define NNODE 512
#define RU 64
#define MEM_DIM 16
#define BOT_DIM 4
#define IN_SZ 66
#define OUT_SZ 256
#define HID (NNODE*RU)          // 32768
#define W3_ROW 16896            // IN_SZ*OUT_SZ
// fp16 frag table: frag f = k*48 + h*24 + fl, fl = ctl*3+ks (ct = h*8+ctl);
// element = lane*8+j. col o = (ct&3)*64+(ct>>2)*16+(lane&15);
// slot s = ks*32+(lane>>4)*8+j ; s<64 -> W row i=s+2 ; s=64,65 -> i=0,1 ; else 0.
#define TAB_HALVES (240*512)    // 122880 halves = 245760 B
#define KSTEP (48*512)          // halves between k-matrices

typedef _Float16 half8 __attribute__((ext_vector_type(8)));
typedef __attribute__((ext_vector_type(4))) float float4v;

__device__ __forceinline__ float fsig(float x) {
    return __builtin_amdgcn_rcpf(1.0f + __expf(-x));
}
__device__ __forceinline__ float ftanh(float x) {
    return 1.0f - 2.0f * __builtin_amdgcn_rcpf(1.0f + __expf(2.0f * x));
}

// ---------------- Kernel 1: prep — fp16 frag table + hypernet m2 --------------
// 248 blocks x 64 threads (1 wave each) -> ~248 CUs active.
// Blocks [0,240): one frag per block. Blocks [240,248): hypernet, 64 nodes each.
__global__ __launch_bounds__(64) void prep_kernel(
    const float* __restrict__ memory, const float* __restrict__ w1,
    const float* __restrict__ b1,     const float* __restrict__ w2,
    const float* __restrict__ b2,     const float* __restrict__ w3,
    const float* __restrict__ b3,     _Float16* __restrict__ tab,
    float* __restrict__ m2_ws)
{
    const int tid = threadIdx.x;
    const int bid = blockIdx.x;
    if (bid < 240) {
        const int f = bid;                  // frag [0,240)
        const int l = tid;                  // [0,64)
        const int k   = f / 48;             // [0,5): w3 rows 0..3, then b3
        const int rem = f - k * 48;         // = ct*3 + ks, ct = h*8+ctl
        const int ct  = rem / 3;
        const int ks  = rem - ct * 3;
        const int q = l & 15, quad = l >> 4;
        const int o = (ct & 3) * 64 + (ct >> 2) * 16 + q;
        const float* src = (k < 4) ? (w3 + k * W3_ROW) : b3;
        half8 v;
        #pragma unroll
        for (int j = 0; j < 8; ++j) {
            const int s = ks * 32 + quad * 8 + j;
            float x = 0.f;
            if (s < IN_SZ) {
                const int i = (s < 64) ? s + 2 : s - 64;
                x = src[i * OUT_SZ + o];
            }
            v[j] = (_Float16)x;
        }
        *(half8*)(tab + f * 512 + l * 8) = v;
    } else {
        const int n = (bid - 240) * 64 + tid;   // [0,512)
        float memv[MEM_DIM];
        #pragma unroll
        for (int j = 0; j < MEM_DIM; ++j) memv[j] = memory[n * MEM_DIM + j];
        float mem1[MEM_DIM];
        #pragma unroll
        for (int t = 0; t < MEM_DIM; ++t) {
            float s = b1[t];
            #pragma unroll
            for (int j = 0; j < MEM_DIM; ++j) s += memv[j] * w1[j * MEM_DIM + t];
            mem1[t] = ftanh(s);
        }
        #pragma unroll
        for (int t = 0; t < BOT_DIM; ++t) {
            float s = b2[t];
            #pragma unroll
            for (int j = 0; j < MEM_DIM; ++j) s += mem1[j] * w2[j * BOT_DIM + t];
            m2_ws[n * 4 + t] = ftanh(s);
        }
    }
}

// ---------------- Kernel 2: fused — block = (node, output-half) ---------------
// grid 1024 = (h=bid>>9, n=bid&511): blocks b and b+512 share the same hx rows
// and (512 % 8 == 0) land on the SAME XCD; with ~4 blocks/CU the whole grid is
// co-resident so the pair reads hx concurrently -> L2 hit. Single 24KB LDS
// buffer, ONE barrier, small register footprint.
__global__ __launch_bounds__(256) void fused_kernel(
    const float* __restrict__ inputs, const float* __restrict__ hx,
    const float* __restrict__ cx,     const float* __restrict__ b_out,
    const _Float16* __restrict__ tab, const float* __restrict__ m2_ws,
    float* __restrict__ out)
{
    __shared__ _Float16 Wl[24 * 512];   // 24576 B, single buffer
    const int tid  = threadIdx.x;
    const int n    = blockIdx.x & 511;
    const int h    = blockIdx.x >> 9;
    const int w    = tid >> 6;
    const int lane = tid & 63;
    const int q    = lane & 15;
    const int quad = lane >> 4;

    // coef splat (fp16 for pk_fma combine)
    const float4v m2v = *(const float4v*)(m2_ws + n * 4);
    half8 vc[4];
    #pragma unroll
    for (int k = 0; k < 4; ++k) {
        const _Float16 c = (_Float16)m2v[k];
        vc[k] = (half8){c, c, c, c, c, c, c, c};
    }

    // ---- A loads (HBM for h=0 blocks; same-XCD L2 hit for h=1 blocks) ----
    float4v xa[2][4];
    float xin[2][2];
    #pragma unroll
    for (int rt = 0; rt < 2; ++rt) {
        const int row = w * 32 + rt * 16 + q;
        const float* hrow = hx + (size_t)row * HID + n * RU + quad * 8;
        xa[rt][0] = *(const float4v*)(hrow);
        xa[rt][1] = *(const float4v*)(hrow + 4);
        xa[rt][2] = *(const float4v*)(hrow + 32);
        xa[rt][3] = *(const float4v*)(hrow + 36);
        if (quad == 0) {
            const float* ip = inputs + (size_t)row * (NNODE * 2) + n * 2;
            xin[rt][0] = ip[0];
            xin[rt][1] = ip[1];
        } else {
            xin[rt][0] = 0.f;
            xin[rt][1] = 0.f;
        }
    }

    // cx for this half (issue early; consumed only in epilogue)
    float cxr[2][4][2];
    #pragma unroll
    for (int rt = 0; rt < 2; ++rt)
        #pragma unroll
        for (int v = 0; v < 4; ++v) {
            const int b = w * 32 + rt * 16 + quad * 4 + v;
            #pragma unroll
            for (int rh = 0; rh < 2; ++rh)
                cxr[rt][v][rh] = cx[(size_t)b * HID + n * RU + h * 32 + rh * 16 + q];
        }

    // b_out for this half: bo[rh][g]
    float bo[2][4];
    #pragma unroll
    for (int rh = 0; rh < 2; ++rh)
        #pragma unroll
        for (int g = 0; g < 4; ++g)
            bo[rh][g] = b_out[g * 64 + h * 32 + rh * 16 + q];

    // ---- combine this half -> Wl (fp16 pk_fma); L2-resident tab ----
    #pragma unroll
    for (int it = 0; it < 6; ++it) {
        const int c  = it * 256 + tid;
        const int fl = c >> 6;
        const int l  = c & 63;
        const _Float16* p = tab + (h * 24 + fl) * 512 + l * 8;
        half8 r = *(const half8*)(p + 4 * KSTEP);     // b3 frag
        r += vc[0] * *(const half8*)(p);
        r += vc[1] * *(const half8*)(p + KSTEP);
        r += vc[2] * *(const half8*)(p + 2 * KSTEP);
        r += vc[3] * *(const half8*)(p + 3 * KSTEP);
        *(half8*)(&Wl[fl * 512 + l * 8]) = r;
    }

    // ---- pack A to fp16 ----
    half8 a[3][2];
    #pragma unroll
    for (int rt = 0; rt < 2; ++rt) {
        #pragma unroll
        for (int ksh = 0; ksh < 2; ++ksh) {
            const float4v lo = xa[rt][ksh * 2];
            const float4v hi = xa[rt][ksh * 2 + 1];
            half8 t;
            t[0] = (_Float16)lo[0]; t[1] = (_Float16)lo[1];
            t[2] = (_Float16)lo[2]; t[3] = (_Float16)lo[3];
            t[4] = (_Float16)hi[0]; t[5] = (_Float16)hi[1];
            t[6] = (_Float16)hi[2]; t[7] = (_Float16)hi[3];
            a[ksh][rt] = t;
        }
        half8 t2 = (half8){0, 0, 0, 0, 0, 0, 0, 0};
        t2[0] = (_Float16)xin[rt][0];
        t2[1] = (_Float16)xin[rt][1];
        a[2][rt] = t2;
    }

    float4v acc[2][8];
    #pragma unroll
    for (int rt = 0; rt < 2; ++rt)
        #pragma unroll
        for (int ctl = 0; ctl < 8; ++ctl)
            acc[rt][ctl] = (float4v){0.f, 0.f, 0.f, 0.f};

    __syncthreads();        // the ONLY barrier

    // ---- MFMA ----
    __builtin_amdgcn_s_setprio(1);
    #pragma unroll
    for (int ks = 0; ks < 3; ++ks)
        #pragma unroll
        for (int ctl = 0; ctl < 8; ++ctl) {
            const half8 bf = *(const half8*)(&Wl[(ctl * 3 + ks) * 512 + lane * 8]);
            acc[0][ctl] = __builtin_amdgcn_mfma_f32_16x16x32_f16(a[ks][0], bf, acc[0][ctl], 0, 0, 0);
            acc[1][ctl] = __builtin_amdgcn_mfma_f32_16x16x32_f16(a[ks][1], bf, acc[1][ctl], 0, 0, 0);
        }
    __builtin_amdgcn_s_setprio(0);

    // ---- epilogue + stores ----
    #pragma unroll
    for (int rt = 0; rt < 2; ++rt)
        #pragma unroll
        for (int v = 0; v < 4; ++v) {
            const int b = w * 32 + rt * 16 + quad * 4 + v;
            const size_t base = (size_t)b * HID + n * RU + h * 32;
            #pragma unroll
            for (int rh = 0; rh < 2; ++rh) {
                // reference: val = sigmoid(matmul) + b_out, THEN gate activations
                float vi = fsig(acc[rt][rh * 4 + 0][v]) + bo[rh][0];
                float vf = fsig(acc[rt][rh * 4 + 1][v]) + bo[rh][1];
                float vg = fsig(acc[rt][rh * 4 + 2][v]) + bo[rh][2];
                float vo = fsig(acc[rt][rh * 4 + 3][v]) + bo[rh][3];
                float it = fsig(vi), ft = fsig(vf);
                float gt = ftanh(vg), ot = fsig(vo);
                float cc = cxr[rt][v][rh] * ft + it * gt;
                const size_t idx = base + rh * 16 + q;
                out[idx] = ot * ftanh(cc);               // hy
                out[(size_t)BATCH * HID + idx] = cc;     // cy
            }
        }
}

extern "C" void kernel_launch(void* const* d_in, const int* in_sizes, int n_in,
                              void* d_out, int out_size, void* d_ws, size_t ws_size,
                              hipStream_t stream) {
    const float* inputs = (const float*)d_in[0];
    const float* hx     = (const float*)d_in[1];
    const float* cx     = (const float*)d_in[2];
    const float* memory = (const float*)d_in[3];
    const float* w1     = (const float*)d_in[4];
    const float* b1     = (const float*)d_in[5];
    const float* w2     = (const float*)d_in[6];
    const float* b2     = (const float*)d_in[7];
    const float* w3     = (const float*)d_in[8];
    const float* b3     = (const float*)d_in[9];
    const float* b_out  = (const float*)d_in[10];
    float* out = (float*)d_out;

    _Float16* tab = (_Float16*)d_ws;                      // 245760 B
    float* m2_ws  = (float*)((char*)d_ws + TAB_HALVES * 2);

    prep_kernel<<<248, 64, 0, stream>>>(memory, w1, b1, w2, b2, w3, b3, tab, m2_ws);
    fused_kernel<<<2 * NNODE, 256, 0, stream>>>(inputs, hx, cx, b_out, tab, m2_ws, out);
}